// Round 8
// baseline (97.015 us; speedup 1.0000x reference)
//
#include <hip/hip_runtime.h>
#include <math.h>

#define WIN 11
#define HALF 5
#define SZ 32
#define PST 33          /* padded LDS row stride */
#define BB 4
#define NG 16
#define NP 64
#define IH 640
#define IW 640
#define NPIX 3072       /* 3*32*32 per crop */
#define NPAIR 4096      /* 4*16*64 */
#define NSLOT 512       /* k_all y-blocks per channel; grid-stride covers count>NSLOT */
#define SSIM_C1 6.5025f
#define SSIM_C2 58.5225f

// exp(-(i-5)^2/4.5)/sum — 11-tap Gaussian, sigma=1.5, compile-time
#define GW_INIT {0.001028379f, 0.007598757f, 0.036000791f, 0.109360748f, \
                 0.213005174f, 0.266011868f, 0.213005174f, 0.109360748f, \
                 0.036000791f, 0.007598757f, 0.001028379f}

// Session lessons encoded:
//  - NO __threadfence (r5: device fence flushes per-XCD L2, +100 µs over 1.5k blocks).
//  - NO contended fp atomicAdd for accumulation (r2/r6 vs r3/r7: +16 µs);
//    unique-cell stores + tiny reduce kernel.
//  - NO memset dispatch: compaction writes count/list with plain stores.
//  - r8: crop staging fused away — per-pair recompute beats serial stage +
//    11.8 MB round trip in a latency-bound regime (VALU was 3.5% busy).

__device__ __forceinline__ bool pair_valid(const float* __restrict__ gt,
                                           const float* __restrict__ pr, int idx) {
    int b = idx >> 10;
    int r = idx & 1023;
    int gi = r >> 6, pi = r & 63;
    const float* g = gt + (b * NG + gi) * 4;
    const float* p = pr + (b * NP + pi) * 4;
    float gx = g[0], gy = g[1], gw = g[2], gh = g[3];
    float px = p[0], py = p[1], pw = p[2], ph = p[3];
    float tlx = fmaxf(gx - gw * 0.5f, px - pw * 0.5f);
    float tly = fmaxf(gy - gh * 0.5f, py - ph * 0.5f);
    float brx = fminf(gx + gw * 0.5f, px + pw * 0.5f);
    float bry = fminf(gy + gh * 0.5f, py + ph * 0.5f);
    float en = ((tlx < brx) && (tly < bry)) ? 1.f : 0.f;
    float ai = (brx - tlx) * (bry - tly) * en;
    float iou = ai / (gw * gh + pw * ph - ai + 1e-16f);
    return (iou > 0.3f && pw > 2.f && ph > 2.f);
}

// ---- validity -> compact list: 1 block, 2-pass wave-local ballot (2 barriers total) ----
__global__ __launch_bounds__(256) void k_valid(const float* __restrict__ gt,
                                               const float* __restrict__ pr,
                                               int* __restrict__ list,
                                               int* __restrict__ count) {
    const int t = threadIdx.x;
    const int wave = t >> 6, lane = t & 63;
    __shared__ int s_wcnt[4];

    // pass 1: count (intra-wave ballots only, no barriers)
    int cnt = 0;
#pragma unroll 1
    for (int i = 0; i < 16; ++i) {
        int idx = wave * 1024 + i * 64 + lane;
        unsigned long long m = __ballot(pair_valid(gt, pr, idx));
        cnt += __popcll(m);
    }
    if (lane == 0) s_wcnt[wave] = cnt;
    __syncthreads();

    int base = 0;
#pragma unroll
    for (int w = 0; w < 4; ++w)
        if (w < wave) base += s_wcnt[w];

    // pass 2: re-evaluate and scatter (boxes L1-hot; VALU trivial)
#pragma unroll 1
    for (int i = 0; i < 16; ++i) {
        int idx = wave * 1024 + i * 64 + lane;
        bool v = pair_valid(gt, pr, idx);
        unsigned long long m = __ballot(v);
        if (v) list[base + __popcll(m & ((1ull << lane) - 1ull))] = idx;
        base += __popcll(m);
    }
    if (t == 0) *count = s_wcnt[0] + s_wcnt[1] + s_wcnt[2] + s_wcnt[3];
}

// per-thread bilinear sample of 4 consecutive pixels in row y of the 32x32 resize
__device__ __forceinline__ void bilinear4(const float* __restrict__ ic,
                                          const float* __restrict__ box,
                                          int y, int xb, float out[4]) {
    float cx = box[0], cy = box[1], bw = box[2], bh = box[3];
    float x0 = fminf(fmaxf(floorf(cx - bw * 0.5f), 0.f), (float)(IW - 1));
    float x1 = fminf(fmaxf(floorf(cx + bw * 0.5f), 0.f), (float)IW);
    float y0 = fminf(fmaxf(floorf(cy - bh * 0.5f), 0.f), (float)(IH - 1));
    float y1 = fminf(fmaxf(floorf(cy + bh * 0.5f), 0.f), (float)IH);
    float wp = fmaxf(x1 - x0, 1.f);
    float hp = fmaxf(y1 - y0, 1.f);
    int xmax = (int)(x0 + wp - 1.f);
    int ymax = (int)(y0 + hp - 1.f);

    float sy = y0 + fminf(fmaxf(((float)y + 0.5f) * hp * (1.f / 32.f) - 0.5f, 0.f), hp - 1.f);
    float fly = floorf(sy);
    int iy0 = (int)fly;
    float fy = sy - fly;
    int iy1 = min(iy0 + 1, ymax);
    const float* r0 = ic + iy0 * IW;
    const float* r1 = ic + iy1 * IW;
#pragma unroll
    for (int j = 0; j < 4; ++j) {
        int x = xb + j;
        float sx = x0 + fminf(fmaxf(((float)x + 0.5f) * wp * (1.f / 32.f) - 0.5f, 0.f), wp - 1.f);
        float flx = floorf(sx);
        int ix0 = (int)flx;
        float fx = sx - flx;
        int ix1 = min(ix0 + 1, xmax);
        float v00 = r0[ix0], v01 = r0[ix1], v10 = r1[ix0], v11 = r1[ix1];
        out[j] = v00 * (1.f - fy) * (1.f - fx) + v01 * (1.f - fy) * fx +
                 v10 * fy * (1.f - fx) + v11 * fy * fx;
    }
}

// ---- fused: per-(valid-pair, channel) crop + mu/sigma + SSIM + L1 ----
__global__ __launch_bounds__(256) void k_all(const int* __restrict__ list,
                                             const int* __restrict__ count,
                                             const float* __restrict__ imgs,
                                             const float* __restrict__ gt,
                                             const float* __restrict__ pr,
                                             float* __restrict__ pairL1,
                                             float* __restrict__ pairSS) {
    const int c = blockIdx.x;      // 0..2
    const int n = *count;
    const int t = threadIdx.x;
    const int y = t >> 3;          // thread owns pixels (y, xb..xb+3)
    const int xb = (t & 7) * 4;
    const int wave = t >> 6, lane = t & 63;

    __shared__ float cg[SZ][PST];   // g crop
    __shared__ float cp[SZ][PST];   // p crop
    __shared__ float hg[SZ][PST];   // h-pass of g
    __shared__ float hg2[SZ][PST];  // h-pass of g^2
    __shared__ float hp_[SZ][PST];  // h-pass of p
    __shared__ float hp2[SZ][PST];  // h-pass of p^2
    __shared__ float hgp[SZ][PST];  // h-pass of g*p
    __shared__ float rl[4], rs[4];
    constexpr float GW[WIN] = GW_INIT;

    for (int slot = blockIdx.y; slot < n; slot += NSLOT) {
        const int pair = list[slot];
        const int b = pair >> 10;
        const int r = pair & 1023;
        const int gi = r >> 6, pi = r & 63;
        const float* gbox = gt + (b * NG + gi) * 4;
        const float* pbox = pr + (b * NP + pi) * 4;
        const float* ic = imgs + ((size_t)b * 3 + c) * IH * IW;

        float gv[4], pv[4];
        bilinear4(ic, gbox, y, xb, gv);
        bilinear4(ic, pbox, y, xb, pv);

        float l1 = 0.f;
#pragma unroll
        for (int j = 0; j < 4; ++j) {
            l1 += fabsf(gv[j] - pv[j]);
            cg[y][xb + j] = gv[j];
            cp[y][xb + j] = pv[j];
        }
        __syncthreads();

        // horizontal pass for all 5 conv inputs (g, g^2, p, p^2, g*p)
#pragma unroll
        for (int j = 0; j < 4; ++j) {
            int x = xb + j;
            float a1 = 0.f, a2 = 0.f, a3 = 0.f, a4 = 0.f, a5 = 0.f;
#pragma unroll
            for (int k = 0; k < WIN; ++k) {
                int xx = x + k - HALF;
                if (xx >= 0 && xx < SZ) {
                    float gval = cg[y][xx];
                    float pval = cp[y][xx];
                    a1 += GW[k] * gval;
                    a2 += GW[k] * gval * gval;
                    a3 += GW[k] * pval;
                    a4 += GW[k] * pval * pval;
                    a5 += GW[k] * gval * pval;
                }
            }
            hg[y][x] = a1;
            hg2[y][x] = a2;
            hp_[y][x] = a3;
            hp2[y][x] = a4;
            hgp[y][x] = a5;
        }
        __syncthreads();

        // vertical pass + SSIM
        float ss = 0.f;
#pragma unroll
        for (int j = 0; j < 4; ++j) {
            int x = xb + j;
            float a1 = 0.f, a2 = 0.f, a3 = 0.f, a4 = 0.f, a5 = 0.f;
#pragma unroll
            for (int k = 0; k < WIN; ++k) {
                int yy = y + k - HALF;
                if (yy >= 0 && yy < SZ) {
                    a1 += GW[k] * hg[yy][x];
                    a2 += GW[k] * hg2[yy][x];
                    a3 += GW[k] * hp_[yy][x];
                    a4 += GW[k] * hp2[yy][x];
                    a5 += GW[k] * hgp[yy][x];
                }
            }
            float m1 = a1, m2 = a3;
            float sg = a2 - m1 * m1;
            float sp = a4 - m2 * m2;
            float sgp = a5 - m1 * m2;
            float num = (2.f * m1 * m2 + SSIM_C1) * (2.f * sgp + SSIM_C2);
            float den = (m1 * m1 + m2 * m2 + SSIM_C1) * (sg + sp + SSIM_C2);
            ss += num / den;
        }

        // block reduction: 64-lane shuffle, then LDS across 4 waves
#pragma unroll
        for (int off = 32; off > 0; off >>= 1) {
            l1 += __shfl_down(l1, off);
            ss += __shfl_down(ss, off);
        }
        if (lane == 0) { rl[wave] = l1; rs[wave] = ss; }
        __syncthreads();
        if (t == 0) {
            pairL1[slot * 3 + c] = rl[0] + rl[1] + rl[2] + rl[3];
            pairSS[slot * 3 + c] = rs[0] + rs[1] + rs[2] + rs[3];
        }
        // next iter's first barrier separates rl/rs reuse; cg/cp rewrite is a
        // different array from the temps read in this iter's v-pass — safe.
    }
}

// ---- finalize: deterministic reduction over compact results ----
__global__ __launch_bounds__(256) void k_final(const int* __restrict__ count,
                                               const float* __restrict__ pairL1,
                                               const float* __restrict__ pairSS,
                                               float* __restrict__ out) {
    const int n3 = (*count) * 3;
    const int t = threadIdx.x;
    float L = 0.f, S = 0.f;
    for (int i = t; i < n3; i += 256) {
        L += pairL1[i];
        S += pairSS[i];
    }
    __shared__ float rl[4], rs[4];
#pragma unroll
    for (int off = 32; off > 0; off >>= 1) {
        L += __shfl_down(L, off);
        S += __shfl_down(S, off);
    }
    const int wave = t >> 6, lane = t & 63;
    if (lane == 0) { rl[wave] = L; rs[wave] = S; }
    __syncthreads();
    if (t == 0) {
        float cnt = (float)(*count);
        float Lt = (rl[0] + rl[1] + rl[2] + rl[3]) * (1.0f / (255.0f * (float)NPIX));
        float St = (rs[0] + rs[1] + rs[2] + rs[3]) * (1.0f / (float)NPIX);
        float m = fmaxf(cnt, 1.f);
        float loss = Lt / m + 1.f - St / m;
        out[0] = (cnt > 0.f) ? loss : 0.f;
    }
}

extern "C" void kernel_launch(void* const* d_in, const int* in_sizes, int n_in,
                              void* d_out, int out_size, void* d_ws, size_t ws_size,
                              hipStream_t stream) {
    const float* imgs = (const float*)d_in[0];  // (4,3,640,640)
    const float* gt = (const float*)d_in[1];    // (4,16,4)
    const float* pr = (const float*)d_in[2];    // (4,64,4)

    float* ws = (float*)d_ws;
    float* pairL1 = ws;                              // 4096*3
    float* pairSS = pairL1 + (size_t)NPAIR * 3;      // 4096*3
    int* list = (int*)(pairSS + (size_t)NPAIR * 3);  // 4096
    int* count = list + NPAIR;                       // 1

    k_valid<<<1, 256, 0, stream>>>(gt, pr, list, count);
    k_all<<<dim3(3, NSLOT), 256, 0, stream>>>(list, count, imgs, gt, pr, pairL1, pairSS);
    k_final<<<1, 256, 0, stream>>>(count, pairL1, pairSS, (float*)d_out);
}

// Round 9
// 94.608 us; speedup vs baseline: 1.0254x; 1.0254x over previous
//
#include <hip/hip_runtime.h>
#include <math.h>

#define WIN 11
#define HALF 5
#define SZ 32
#define PST 33          /* padded LDS row stride */
#define BB 4
#define NG 16
#define NP 64
#define IH 640
#define IW 640
#define CPIX 1024       /* 32*32 per channel */
#define NPIX 3072       /* 3*32*32 per crop */
#define NCROP 320       /* 64 gt + 256 pred */
#define NPAIR 4096      /* 4*16*64 */
#define NSLOT 384       /* k_pair y-blocks per channel */
#define SSIM_C1 6.5025f
#define SSIM_C2 58.5225f

// exp(-(i-5)^2/4.5)/sum — 11-tap Gaussian, sigma=1.5, compile-time
#define GW_INIT {0.001028379f, 0.007598757f, 0.036000791f, 0.109360748f, \
                 0.213005174f, 0.266011868f, 0.213005174f, 0.109360748f, \
                 0.036000791f, 0.007598757f, 0.001028379f}

// Session lessons encoded:
//  - NO __threadfence (r5: device-scope fence flushes per-XCD L2; +100 µs over 1.5k blocks).
//  - NO contended fp atomicAdd accumulation (r2/r6 vs r3/r7: +16 µs); unique-cell
//    stores + tiny reduce kernel.
//  - NO memset dispatch: ballot compaction writes count/list with plain stores.
//  - r8: do NOT re-gather crops per pair — scattered bilinear gathers are the
//    expensive op (~1800 vs 960 gathers = +9 µs). Stage crops once (r7-fast),
//    but move the 5 convs to k_pair where inputs are coalesced/L2-hot (r9).

__device__ __forceinline__ bool pair_valid(const float* __restrict__ gt,
                                           const float* __restrict__ pr, int idx) {
    int b = idx >> 10;
    int r = idx & 1023;
    int gi = r >> 6, pi = r & 63;
    const float* g = gt + (b * NG + gi) * 4;
    const float* p = pr + (b * NP + pi) * 4;
    float gx = g[0], gy = g[1], gw = g[2], gh = g[3];
    float px = p[0], py = p[1], pw = p[2], ph = p[3];
    float tlx = fmaxf(gx - gw * 0.5f, px - pw * 0.5f);
    float tly = fmaxf(gy - gh * 0.5f, py - ph * 0.5f);
    float brx = fminf(gx + gw * 0.5f, px + pw * 0.5f);
    float bry = fminf(gy + gh * 0.5f, py + ph * 0.5f);
    float en = ((tlx < brx) && (tly < bry)) ? 1.f : 0.f;
    float ai = (brx - tlx) * (bry - tly) * en;
    float iou = ai / (gw * gh + pw * ph - ai + 1e-16f);
    return (iou > 0.3f && pw > 2.f && ph > 2.f);
}

// ---- fused: crop gather+store (blocks 0..959, no LDS/no barriers) | validity (block 960) ----
__global__ __launch_bounds__(256) void k_crop_valid(const float* __restrict__ imgs,
                                                    const float* __restrict__ gt,
                                                    const float* __restrict__ pr,
                                                    float* __restrict__ crops,
                                                    int* __restrict__ list,
                                                    int* __restrict__ count) {
    const int blk = blockIdx.x;
    const int t = threadIdx.x;
    const int wave = t >> 6, lane = t & 63;

    if (blk == 3 * NCROP) {
        // ---- validity -> compact list: 2-pass wave-local ballot, 1 barrier ----
        __shared__ int s_wcnt[4];
        int cnt = 0;
#pragma unroll 1
        for (int i = 0; i < 16; ++i) {
            unsigned long long m = __ballot(pair_valid(gt, pr, wave * 1024 + i * 64 + lane));
            cnt += __popcll(m);
        }
        if (lane == 0) s_wcnt[wave] = cnt;
        __syncthreads();
        int base = 0;
#pragma unroll
        for (int w = 0; w < 4; ++w)
            if (w < wave) base += s_wcnt[w];
#pragma unroll 1
        for (int i = 0; i < 16; ++i) {
            int idx = wave * 1024 + i * 64 + lane;
            bool v = pair_valid(gt, pr, idx);
            unsigned long long m = __ballot(v);
            if (v) list[base + __popcll(m & ((1ull << lane) - 1ull))] = idx;
            base += __popcll(m);
        }
        if (t == 0) *count = s_wcnt[0] + s_wcnt[1] + s_wcnt[2] + s_wcnt[3];
        return;
    }

    // ---- crop path: pure gather + store ----
    const int crop = blk / 3;
    const int c = blk - crop * 3;
    int b;
    const float* box;
    if (crop < BB * NG) {
        b = crop >> 4;
        box = gt + crop * 4;
    } else {
        int id = crop - BB * NG;
        b = id >> 6;
        box = pr + id * 4;
    }

    // box is wave-uniform -> scalar loads
    float cx = box[0], cy = box[1], bw = box[2], bh = box[3];
    float x0 = fminf(fmaxf(floorf(cx - bw * 0.5f), 0.f), (float)(IW - 1));
    float x1 = fminf(fmaxf(floorf(cx + bw * 0.5f), 0.f), (float)IW);
    float y0 = fminf(fmaxf(floorf(cy - bh * 0.5f), 0.f), (float)(IH - 1));
    float y1 = fminf(fmaxf(floorf(cy + bh * 0.5f), 0.f), (float)IH);
    float wp = fmaxf(x1 - x0, 1.f);
    float hp = fmaxf(y1 - y0, 1.f);
    int xmax = (int)(x0 + wp - 1.f);
    int ymax = (int)(y0 + hp - 1.f);

    const int y = t >> 3;          // thread owns pixels (y, xb..xb+3)
    const int xb = (t & 7) * 4;

    float sy = y0 + fminf(fmaxf(((float)y + 0.5f) * hp * (1.f / 32.f) - 0.5f, 0.f), hp - 1.f);
    float fly = floorf(sy);
    int iy0 = (int)fly;
    float fy = sy - fly;
    int iy1 = min(iy0 + 1, ymax);

    const float* ic = imgs + ((size_t)b * 3 + c) * IH * IW;
    const float* r0 = ic + iy0 * IW;
    const float* r1 = ic + iy1 * IW;
    float vv[4];
#pragma unroll
    for (int j = 0; j < 4; ++j) {
        int x = xb + j;
        float sx = x0 + fminf(fmaxf(((float)x + 0.5f) * wp * (1.f / 32.f) - 0.5f, 0.f), wp - 1.f);
        float flx = floorf(sx);
        int ix0 = (int)flx;
        float fx = sx - flx;
        int ix1 = min(ix0 + 1, xmax);
        float v00 = r0[ix0], v01 = r0[ix1], v10 = r1[ix0], v11 = r1[ix1];
        vv[j] = v00 * (1.f - fy) * (1.f - fx) + v01 * (1.f - fy) * fx +
                v10 * fy * (1.f - fx) + v11 * fy * fx;
    }
    float* dst = crops + (size_t)crop * NPIX + c * CPIX + t * 4;
    *(float4*)dst = make_float4(vv[0], vv[1], vv[2], vv[3]);
}

// ---- per-(valid-pair, channel): load 2 staged crops, all 5 convs, SSIM + L1 ----
__global__ __launch_bounds__(256) void k_pair(const int* __restrict__ list,
                                              const int* __restrict__ count,
                                              const float* __restrict__ crops,
                                              float* __restrict__ pairL1,
                                              float* __restrict__ pairSS) {
    const int c = blockIdx.x;      // 0..2
    const int n = *count;
    const int t = threadIdx.x;
    const int y = t >> 3;
    const int xb = (t & 7) * 4;
    const int wave = t >> 6, lane = t & 63;

    __shared__ float cg[SZ][PST];   // g crop
    __shared__ float cp[SZ][PST];   // p crop
    __shared__ float hg[SZ][PST];   // h-pass of g
    __shared__ float hg2[SZ][PST];  // h-pass of g^2
    __shared__ float hp_[SZ][PST];  // h-pass of p
    __shared__ float hp2[SZ][PST];  // h-pass of p^2
    __shared__ float hgp[SZ][PST];  // h-pass of g*p
    __shared__ float rl[4], rs[4];
    constexpr float GW[WIN] = GW_INIT;

    for (int slot = blockIdx.y; slot < n; slot += NSLOT) {
        const int pair = list[slot];
        const int b = pair >> 10;
        const int r = pair & 1023;
        const int gi = r >> 6, pi = r & 63;
        const size_t goff = (size_t)(b * NG + gi) * NPIX + c * CPIX;
        const size_t poff = (size_t)(BB * NG + b * NP + pi) * NPIX + c * CPIX;

        float4 gv = *(const float4*)(crops + goff + t * 4);
        float4 pv = *(const float4*)(crops + poff + t * 4);
        float l1 = fabsf(gv.x - pv.x) + fabsf(gv.y - pv.y) +
                   fabsf(gv.z - pv.z) + fabsf(gv.w - pv.w);
        cg[y][xb + 0] = gv.x; cp[y][xb + 0] = pv.x;
        cg[y][xb + 1] = gv.y; cp[y][xb + 1] = pv.y;
        cg[y][xb + 2] = gv.z; cp[y][xb + 2] = pv.z;
        cg[y][xb + 3] = gv.w; cp[y][xb + 3] = pv.w;
        __syncthreads();

        // horizontal pass for all 5 conv inputs (g, g^2, p, p^2, g*p)
#pragma unroll
        for (int j = 0; j < 4; ++j) {
            int x = xb + j;
            float a1 = 0.f, a2 = 0.f, a3 = 0.f, a4 = 0.f, a5 = 0.f;
#pragma unroll
            for (int k = 0; k < WIN; ++k) {
                int xx = x + k - HALF;
                if (xx >= 0 && xx < SZ) {
                    float gval = cg[y][xx];
                    float pval = cp[y][xx];
                    a1 += GW[k] * gval;
                    a2 += GW[k] * gval * gval;
                    a3 += GW[k] * pval;
                    a4 += GW[k] * pval * pval;
                    a5 += GW[k] * gval * pval;
                }
            }
            hg[y][x] = a1;
            hg2[y][x] = a2;
            hp_[y][x] = a3;
            hp2[y][x] = a4;
            hgp[y][x] = a5;
        }
        __syncthreads();

        // vertical pass + SSIM
        float ss = 0.f;
#pragma unroll
        for (int j = 0; j < 4; ++j) {
            int x = xb + j;
            float a1 = 0.f, a2 = 0.f, a3 = 0.f, a4 = 0.f, a5 = 0.f;
#pragma unroll
            for (int k = 0; k < WIN; ++k) {
                int yy = y + k - HALF;
                if (yy >= 0 && yy < SZ) {
                    a1 += GW[k] * hg[yy][x];
                    a2 += GW[k] * hg2[yy][x];
                    a3 += GW[k] * hp_[yy][x];
                    a4 += GW[k] * hp2[yy][x];
                    a5 += GW[k] * hgp[yy][x];
                }
            }
            float m1 = a1, m2 = a3;
            float sg = a2 - m1 * m1;
            float sp = a4 - m2 * m2;
            float sgp = a5 - m1 * m2;
            float num = (2.f * m1 * m2 + SSIM_C1) * (2.f * sgp + SSIM_C2);
            float den = (m1 * m1 + m2 * m2 + SSIM_C1) * (sg + sp + SSIM_C2);
            ss += num / den;
        }

        // block reduction: 64-lane shuffle, then LDS across 4 waves
#pragma unroll
        for (int off = 32; off > 0; off >>= 1) {
            l1 += __shfl_down(l1, off);
            ss += __shfl_down(ss, off);
        }
        if (lane == 0) { rl[wave] = l1; rs[wave] = ss; }
        __syncthreads();
        if (t == 0) {
            pairL1[slot * 3 + c] = rl[0] + rl[1] + rl[2] + rl[3];
            pairSS[slot * 3 + c] = rs[0] + rs[1] + rs[2] + rs[3];
        }
        // next iter's cg/cp-fill barrier separates rl/rs reuse — safe.
    }
}

// ---- finalize: deterministic reduction over compact results ----
__global__ __launch_bounds__(256) void k_final(const int* __restrict__ count,
                                               const float* __restrict__ pairL1,
                                               const float* __restrict__ pairSS,
                                               float* __restrict__ out) {
    const int n3 = (*count) * 3;
    const int t = threadIdx.x;
    float L = 0.f, S = 0.f;
    for (int i = t; i < n3; i += 256) {
        L += pairL1[i];
        S += pairSS[i];
    }
    __shared__ float rl[4], rs[4];
#pragma unroll
    for (int off = 32; off > 0; off >>= 1) {
        L += __shfl_down(L, off);
        S += __shfl_down(S, off);
    }
    const int wave = t >> 6, lane = t & 63;
    if (lane == 0) { rl[wave] = L; rs[wave] = S; }
    __syncthreads();
    if (t == 0) {
        float cnt = (float)(*count);
        float Lt = (rl[0] + rl[1] + rl[2] + rl[3]) * (1.0f / (255.0f * (float)NPIX));
        float St = (rs[0] + rs[1] + rs[2] + rs[3]) * (1.0f / (float)NPIX);
        float m = fmaxf(cnt, 1.f);
        float loss = Lt / m + 1.f - St / m;
        out[0] = (cnt > 0.f) ? loss : 0.f;
    }
}

extern "C" void kernel_launch(void* const* d_in, const int* in_sizes, int n_in,
                              void* d_out, int out_size, void* d_ws, size_t ws_size,
                              hipStream_t stream) {
    const float* imgs = (const float*)d_in[0];  // (4,3,640,640)
    const float* gt = (const float*)d_in[1];    // (4,16,4)
    const float* pr = (const float*)d_in[2];    // (4,64,4)

    float* ws = (float*)d_ws;
    float* crops = ws;                                   // 320*3072
    float* pairL1 = crops + (size_t)NCROP * NPIX;        // 4096*3
    float* pairSS = pairL1 + (size_t)NPAIR * 3;          // 4096*3
    int* list = (int*)(pairSS + (size_t)NPAIR * 3);      // 4096
    int* count = list + NPAIR;                           // 1

    k_crop_valid<<<3 * NCROP + 1, 256, 0, stream>>>(imgs, gt, pr, crops, list, count);
    k_pair<<<dim3(3, NSLOT), 256, 0, stream>>>(list, count, crops, pairL1, pairSS);
    k_final<<<1, 256, 0, stream>>>(count, pairL1, pairSS, (float*)d_out);
}

// Round 10
// 87.452 us; speedup vs baseline: 1.1093x; 1.0818x over previous
//
#include <hip/hip_runtime.h>
#include <math.h>

#define WIN 11
#define HALF 5
#define SZ 32
#define PST 33          /* padded LDS row stride */
#define BB 4
#define NG 16
#define NP 64
#define IH 640
#define IW 640
#define CPIX 1024       /* 32*32 per channel */
#define NPIX 3072       /* 3*32*32 per crop */
#define NCROP 320       /* 64 gt + 256 pred */
#define NPAIR 4096      /* 4*16*64 */
#define NSLOT 512       /* k_pair y-blocks per channel */
#define SSIM_C1 6.5025f
#define SSIM_C2 58.5225f

// exp(-(i-5)^2/4.5)/sum — 11-tap Gaussian, sigma=1.5, compile-time
#define GW_INIT {0.001028379f, 0.007598757f, 0.036000791f, 0.109360748f, \
                 0.213005174f, 0.266011868f, 0.213005174f, 0.109360748f, \
                 0.036000791f, 0.007598757f, 0.001028379f}

// Session lessons encoded:
//  - NO __threadfence (r5: device-scope fence flushes per-XCD L2; +100 µs over 1.5k blocks).
//  - NO contended fp atomicAdd accumulation (r2/r6 vs r3/r7: +16 µs); unique-cell
//    stores + tiny reduce kernel.
//  - NO memset dispatch: ballot compaction writes count/list with plain stores.
//  - r8: do NOT re-gather crops per pair (scattered gathers are the expensive op).
//  - r9: do NOT move per-crop stats (mu/sigma convs) into the per-pair kernel
//    (2.8x conv work + 30KB LDS = +6 µs). Compute each quantity at the loop
//    level where it naturally lives. r7 split is optimal so far.
//  - r10: bilinear gather via float2 (16->8 load instrs; clamp edges have
//    weight exactly 0 so result is bitwise identical).

__device__ __forceinline__ bool pair_valid(const float* __restrict__ gt,
                                           const float* __restrict__ pr, int idx) {
    int b = idx >> 10;
    int r = idx & 1023;
    int gi = r >> 6, pi = r & 63;
    const float* g = gt + (b * NG + gi) * 4;
    const float* p = pr + (b * NP + pi) * 4;
    float gx = g[0], gy = g[1], gw = g[2], gh = g[3];
    float px = p[0], py = p[1], pw = p[2], ph = p[3];
    float tlx = fmaxf(gx - gw * 0.5f, px - pw * 0.5f);
    float tly = fmaxf(gy - gh * 0.5f, py - ph * 0.5f);
    float brx = fminf(gx + gw * 0.5f, px + pw * 0.5f);
    float bry = fminf(gy + gh * 0.5f, py + ph * 0.5f);
    float en = ((tlx < brx) && (tly < bry)) ? 1.f : 0.f;
    float ai = (brx - tlx) * (bry - tly) * en;
    float iou = ai / (gw * gh + pw * ph - ai + 1e-16f);
    return (iou > 0.3f && pw > 2.f && ph > 2.f);
}

// ---- fused: crop + mu/sigma (blocks 0..959) | validity compaction (block 960) ----
__global__ __launch_bounds__(256) void k_crop_valid(const float* __restrict__ imgs,
                                                    const float* __restrict__ gt,
                                                    const float* __restrict__ pr,
                                                    float* __restrict__ crops,
                                                    float* __restrict__ mus,
                                                    float* __restrict__ sigs,
                                                    int* __restrict__ list,
                                                    int* __restrict__ count) {
    const int blk = blockIdx.x;
    const int t = threadIdx.x;
    const int wave = t >> 6, lane = t & 63;

    if (blk == 3 * NCROP) {
        // ---- validity -> compact list: 2-pass wave-local ballot, 1 barrier ----
        __shared__ int s_wcnt[4];
        int cnt = 0;
#pragma unroll 1
        for (int i = 0; i < 16; ++i) {
            unsigned long long m = __ballot(pair_valid(gt, pr, wave * 1024 + i * 64 + lane));
            cnt += __popcll(m);
        }
        if (lane == 0) s_wcnt[wave] = cnt;
        __syncthreads();
        int base = 0;
#pragma unroll
        for (int w = 0; w < 4; ++w)
            if (w < wave) base += s_wcnt[w];
#pragma unroll 1
        for (int i = 0; i < 16; ++i) {
            int idx = wave * 1024 + i * 64 + lane;
            bool v = pair_valid(gt, pr, idx);
            unsigned long long m = __ballot(v);
            if (v) list[base + __popcll(m & ((1ull << lane) - 1ull))] = idx;
            base += __popcll(m);
        }
        if (t == 0) *count = s_wcnt[0] + s_wcnt[1] + s_wcnt[2] + s_wcnt[3];
        return;
    }

    // ---- crop path: per-thread bilinear indices, float2 gathers ----
    const int crop = blk / 3;
    const int c = blk - crop * 3;
    int b;
    const float* box;
    if (crop < BB * NG) {
        b = crop >> 4;
        box = gt + crop * 4;
    } else {
        int id = crop - BB * NG;
        b = id >> 6;
        box = pr + id * 4;
    }

    __shared__ float cr[SZ][PST];
    __shared__ float t1[SZ][PST];
    __shared__ float t2[SZ][PST];

    // box is wave-uniform -> scalar loads
    float cx = box[0], cy = box[1], bw = box[2], bh = box[3];
    float x0 = fminf(fmaxf(floorf(cx - bw * 0.5f), 0.f), (float)(IW - 1));
    float x1 = fminf(fmaxf(floorf(cx + bw * 0.5f), 0.f), (float)IW);
    float y0 = fminf(fmaxf(floorf(cy - bh * 0.5f), 0.f), (float)(IH - 1));
    float y1 = fminf(fmaxf(floorf(cy + bh * 0.5f), 0.f), (float)IH);
    float wp = fmaxf(x1 - x0, 1.f);
    float hp = fmaxf(y1 - y0, 1.f);
    int xmax = (int)(x0 + wp - 1.f);
    int ymax = (int)(y0 + hp - 1.f);

    const int y = t >> 3;          // thread owns pixels (y, xb..xb+3)
    const int xb = (t & 7) * 4;

    float sy = y0 + fminf(fmaxf(((float)y + 0.5f) * hp * (1.f / 32.f) - 0.5f, 0.f), hp - 1.f);
    float fly = floorf(sy);
    int iy0 = (int)fly;
    float fy = sy - fly;
    int iy1 = min(iy0 + 1, ymax);

    const float* ic = imgs + ((size_t)b * 3 + c) * IH * IW;
    const float* r0 = ic + iy0 * IW;
    const float* r1 = ic + iy1 * IW;
    float vv[4];
#pragma unroll
    for (int j = 0; j < 4; ++j) {
        int x = xb + j;
        float sx = x0 + fminf(fmaxf(((float)x + 0.5f) * wp * (1.f / 32.f) - 0.5f, 0.f), wp - 1.f);
        float flx = floorf(sx);
        int ix0 = (int)flx;
        float fx = sx - flx;
        // float2 gather: ix1==ix0+1 except at the clamp edge; clamped/degenerate
        // lanes have fx==0 or select f.y, so result is bitwise identical to the
        // 4-scalar-load version (0-weight taps multiply a finite value).
        int ixb = max(min(ix0, xmax - 1), 0);
        bool cl = (ix0 > ixb);     // ix0 was at xmax: duplicate high element
        float2 q0 = *(const float2*)(r0 + ixb);
        float2 q1 = *(const float2*)(r1 + ixb);
        float v00 = cl ? q0.y : q0.x;
        float v01 = q0.y;
        float v10 = cl ? q1.y : q1.x;
        float v11 = q1.y;
        vv[j] = v00 * (1.f - fy) * (1.f - fx) + v01 * (1.f - fy) * fx +
                v10 * fy * (1.f - fx) + v11 * fy * fx;
        cr[y][x] = vv[j];
    }
    float* dst = crops + (size_t)crop * NPIX + c * CPIX + t * 4;
    *(float4*)dst = make_float4(vv[0], vv[1], vv[2], vv[3]);
    __syncthreads();

    constexpr float GW[WIN] = GW_INIT;
    // horizontal pass on x and x^2
#pragma unroll
    for (int j = 0; j < 4; ++j) {
        int x = xb + j;
        float a1 = 0.f, a2 = 0.f;
#pragma unroll
        for (int k = 0; k < WIN; ++k) {
            int xx = x + k - HALF;
            if (xx >= 0 && xx < SZ) {
                float v = cr[y][xx];
                a1 += GW[k] * v;
                a2 += GW[k] * v * v;
            }
        }
        t1[y][x] = a1;
        t2[y][x] = a2;
    }
    __syncthreads();
    // vertical pass
    float m[4], s[4];
#pragma unroll
    for (int j = 0; j < 4; ++j) {
        int x = xb + j;
        float a1 = 0.f, a2 = 0.f;
#pragma unroll
        for (int k = 0; k < WIN; ++k) {
            int yy = y + k - HALF;
            if (yy >= 0 && yy < SZ) {
                a1 += GW[k] * t1[yy][x];
                a2 += GW[k] * t2[yy][x];
            }
        }
        m[j] = a1;
        s[j] = a2 - a1 * a1;
    }
    float* mdst = mus + (size_t)crop * NPIX + c * CPIX + t * 4;
    float* sdst = sigs + (size_t)crop * NPIX + c * CPIX + t * 4;
    *(float4*)mdst = make_float4(m[0], m[1], m[2], m[3]);
    *(float4*)sdst = make_float4(s[0], s[1], s[2], s[3]);
}

// ---- per-(valid-pair, channel) SSIM + L1; unique-cell stores (r3/r7-measured-fast) ----
__global__ __launch_bounds__(256) void k_pair(const int* __restrict__ list,
                                              const int* __restrict__ count,
                                              const float* __restrict__ crops,
                                              const float* __restrict__ mus,
                                              const float* __restrict__ sigs,
                                              float* __restrict__ pairL1,
                                              float* __restrict__ pairSS) {
    const int c = blockIdx.x;      // 0..2
    const int n = *count;
    const int t = threadIdx.x;
    const int y = t >> 3;
    const int xb = (t & 7) * 4;
    const int wave = t >> 6, lane = t & 63;

    __shared__ float gp[SZ][PST];
    __shared__ float tmp[SZ][PST];
    __shared__ float rl[4], rs[4];
    constexpr float GW[WIN] = GW_INIT;

    for (int slot = blockIdx.y; slot < n; slot += NSLOT) {
        const int pair = list[slot];
        const int b = pair >> 10;
        const int r = pair & 1023;
        const int gi = r >> 6, pi = r & 63;
        const size_t goff = (size_t)(b * NG + gi) * NPIX + c * CPIX;
        const size_t poff = (size_t)(BB * NG + b * NP + pi) * NPIX + c * CPIX;

        float4 gv = *(const float4*)(crops + goff + t * 4);
        float4 pv = *(const float4*)(crops + poff + t * 4);
        // hoist mu/sigma loads: in flight across both conv phases
        float4 mg = *(const float4*)(mus + goff + t * 4);
        float4 mp = *(const float4*)(mus + poff + t * 4);
        float4 sg = *(const float4*)(sigs + goff + t * 4);
        float4 sp = *(const float4*)(sigs + poff + t * 4);

        float l1 = fabsf(gv.x - pv.x) + fabsf(gv.y - pv.y) +
                   fabsf(gv.z - pv.z) + fabsf(gv.w - pv.w);
        gp[y][xb + 0] = gv.x * pv.x;
        gp[y][xb + 1] = gv.y * pv.y;
        gp[y][xb + 2] = gv.z * pv.z;
        gp[y][xb + 3] = gv.w * pv.w;
        __syncthreads();

#pragma unroll
        for (int j = 0; j < 4; ++j) {
            int x = xb + j;
            float a = 0.f;
#pragma unroll
            for (int k = 0; k < WIN; ++k) {
                int xx = x + k - HALF;
                if (xx >= 0 && xx < SZ) a += GW[k] * gp[y][xx];
            }
            tmp[y][x] = a;
        }
        __syncthreads();

        float mgv[4] = {mg.x, mg.y, mg.z, mg.w};
        float mpv[4] = {mp.x, mp.y, mp.z, mp.w};
        float sgv[4] = {sg.x, sg.y, sg.z, sg.w};
        float spv[4] = {sp.x, sp.y, sp.z, sp.w};
        float ss = 0.f;
#pragma unroll
        for (int j = 0; j < 4; ++j) {
            int x = xb + j;
            float a = 0.f;
#pragma unroll
            for (int k = 0; k < WIN; ++k) {
                int yy = y + k - HALF;
                if (yy >= 0 && yy < SZ) a += GW[k] * tmp[yy][x];
            }
            float m1 = mgv[j], m2 = mpv[j];
            float sgp = a - m1 * m2;
            float num = (2.f * m1 * m2 + SSIM_C1) * (2.f * sgp + SSIM_C2);
            float den = (m1 * m1 + m2 * m2 + SSIM_C1) * (sgv[j] + spv[j] + SSIM_C2);
            ss += num / den;
        }

        // block reduction: 64-lane shuffle, then LDS across 4 waves
#pragma unroll
        for (int off = 32; off > 0; off >>= 1) {
            l1 += __shfl_down(l1, off);
            ss += __shfl_down(ss, off);
        }
        if (lane == 0) { rl[wave] = l1; rs[wave] = ss; }
        __syncthreads();
        if (t == 0) {
            pairL1[slot * 3 + c] = rl[0] + rl[1] + rl[2] + rl[3];
            pairSS[slot * 3 + c] = rs[0] + rs[1] + rs[2] + rs[3];
        }
    }
}

// ---- finalize: deterministic reduction over compact results ----
__global__ __launch_bounds__(256) void k_final(const int* __restrict__ count,
                                               const float* __restrict__ pairL1,
                                               const float* __restrict__ pairSS,
                                               float* __restrict__ out) {
    const int n3 = (*count) * 3;
    const int t = threadIdx.x;
    float L = 0.f, S = 0.f;
    for (int i = t; i < n3; i += 256) {
        L += pairL1[i];
        S += pairSS[i];
    }
    __shared__ float rl[4], rs[4];
#pragma unroll
    for (int off = 32; off > 0; off >>= 1) {
        L += __shfl_down(L, off);
        S += __shfl_down(S, off);
    }
    const int wave = t >> 6, lane = t & 63;
    if (lane == 0) { rl[wave] = L; rs[wave] = S; }
    __syncthreads();
    if (t == 0) {
        float cnt = (float)(*count);
        float Lt = (rl[0] + rl[1] + rl[2] + rl[3]) * (1.0f / (255.0f * (float)NPIX));
        float St = (rs[0] + rs[1] + rs[2] + rs[3]) * (1.0f / (float)NPIX);
        float m = fmaxf(cnt, 1.f);
        float loss = Lt / m + 1.f - St / m;
        out[0] = (cnt > 0.f) ? loss : 0.f;
    }
}

extern "C" void kernel_launch(void* const* d_in, const int* in_sizes, int n_in,
                              void* d_out, int out_size, void* d_ws, size_t ws_size,
                              hipStream_t stream) {
    const float* imgs = (const float*)d_in[0];  // (4,3,640,640)
    const float* gt = (const float*)d_in[1];    // (4,16,4)
    const float* pr = (const float*)d_in[2];    // (4,64,4)

    float* ws = (float*)d_ws;
    float* crops = ws;                                   // 320*3072
    float* mus = crops + (size_t)NCROP * NPIX;
    float* sigs = mus + (size_t)NCROP * NPIX;
    float* pairL1 = sigs + (size_t)NCROP * NPIX;         // 4096*3
    float* pairSS = pairL1 + (size_t)NPAIR * 3;          // 4096*3
    int* list = (int*)(pairSS + (size_t)NPAIR * 3);      // 4096
    int* count = list + NPAIR;                           // 1

    k_crop_valid<<<3 * NCROP + 1, 256, 0, stream>>>(imgs, gt, pr, crops, mus, sigs,
                                                    list, count);
    k_pair<<<dim3(3, NSLOT), 256, 0, stream>>>(list, count, crops, mus, sigs,
                                               pairL1, pairSS);
    k_final<<<1, 256, 0, stream>>>(count, pairL1, pairSS, (float*)d_out);
}